// Round 2
// baseline (3118.568 us; speedup 1.0000x reference)
//
#include <hip/hip_runtime.h>
#include <hip/hip_bf16.h>
#include <math.h>

typedef __hip_bfloat16 bf16;
typedef __hip_bfloat162 bf162;

__device__ __forceinline__ float b2f(bf16 x){ return __bfloat162float(x); }
__device__ __forceinline__ bf16  f2b(float x){ return __float2bfloat16(x); }

constexpr int kH = 112, kW = 112, kC = 128, kHeads = 4, kWS = 7;
constexpr int kN = 49, kHD = 32, kL = kH * kW;      // L = 12544
constexpr int kWinElems = kN * kC;                  // 6272
constexpr int kMLP = 512;
constexpr float kEps = 1e-5f;
constexpr float kScale = 0.17677669529663687f;      // 1/sqrt(32)

// ---------------------------------------------------------------------------
// K1: LN(x), LN(v) + window partition + Q/K/V projection. fp32 in, bf16 out.
// One block per window (4096 blocks, 256 threads).
__global__ __launch_bounds__(256) void k_ln_qkv(
    const float* __restrict__ x, const float* __restrict__ v,
    const float* __restrict__ n1g, const float* __restrict__ n1b,
    const float* __restrict__ nvg, const float* __restrict__ nvb,
    const float* __restrict__ qw, const float* __restrict__ qb,
    const float* __restrict__ kvw, const float* __restrict__ kvb,
    bf16* __restrict__ qo, bf16* __restrict__ ko, bf16* __restrict__ vo)
{
    __shared__ float xn[kN][kC + 1];   // +1 pad: bank-conflict-free row access
    __shared__ float vn[kN][kC + 1];
    const int wb = blockIdx.x;
    const int b = wb >> 8, wy = (wb >> 4) & 15, wx = wb & 15;
    const int tid = threadIdx.x, wave = tid >> 6, lane = tid & 63;
    const int c0 = lane * 2, c1 = c0 + 1;

    // LN phase: one wave per row, 2 elems per lane, butterfly reduce.
    for (int n = wave; n < kN; n += 4) {
        const int hh = wy * kWS + n / 7, ww = wx * kWS + n % 7;
        const size_t r = ((size_t)b * kL + (size_t)hh * kW + ww) * kC;
        const float2 xv = *(const float2*)(x + r + c0);
        const float2 vv = *(const float2*)(v + r + c0);
        float sx = xv.x + xv.y, qx = xv.x * xv.x + xv.y * xv.y;
        float sv = vv.x + vv.y, qv = vv.x * vv.x + vv.y * vv.y;
        #pragma unroll
        for (int off = 32; off > 0; off >>= 1) {
            sx += __shfl_xor(sx, off); qx += __shfl_xor(qx, off);
            sv += __shfl_xor(sv, off); qv += __shfl_xor(qv, off);
        }
        const float mux = sx * (1.f / kC);
        const float ivx = rsqrtf(qx * (1.f / kC) - mux * mux + kEps);
        const float muv = sv * (1.f / kC);
        const float ivv = rsqrtf(qv * (1.f / kC) - muv * muv + kEps);
        xn[n][c0] = (xv.x - mux) * ivx * n1g[c0] + n1b[c0];
        xn[n][c1] = (xv.y - mux) * ivx * n1g[c1] + n1b[c1];
        vn[n][c0] = (vv.x - muv) * ivv * nvg[c0] + nvb[c0];
        vn[n][c1] = (vv.y - muv) * ivv * nvg[c1] + nvb[c1];
    }
    __syncthreads();

    // Projection: tasks = 7 row-tiles x {q,k,v} x 64 co-pairs = 1344.
    for (int task = tid; task < 1344; task += 256) {
        const int tile = task / 192, rem = task % 192;
        const int p = rem >> 6, co = (rem & 63) * 2;
        const int n0 = tile * 7;
        const float (*src)[kC + 1] = (p == 0) ? xn : vn;
        const float* w = (p == 0) ? qw : kvw;
        const int row = (p == 2) ? (128 + co) : co;
        const float4* w0 = (const float4*)(w + (size_t)row * kC);
        const float4* w1 = (const float4*)(w + (size_t)(row + 1) * kC);
        const float* bias = (p == 0) ? qb : kvb;
        float acc0[7], acc1[7];
        const float bi0 = bias[row], bi1 = bias[row + 1];
        #pragma unroll
        for (int r = 0; r < 7; r++) { acc0[r] = bi0; acc1[r] = bi1; }
        for (int ci = 0; ci < 32; ci++) {
            const float4 wa = w0[ci];
            const float4 wbv = w1[ci];
            #pragma unroll
            for (int r = 0; r < 7; r++) {
                const float s0 = src[n0 + r][4 * ci],     s1 = src[n0 + r][4 * ci + 1];
                const float s2 = src[n0 + r][4 * ci + 2], s3 = src[n0 + r][4 * ci + 3];
                acc0[r] += wa.x * s0 + wa.y * s1 + wa.z * s2 + wa.w * s3;
                acc1[r] += wbv.x * s0 + wbv.y * s1 + wbv.z * s2 + wbv.w * s3;
            }
        }
        bf16* dst = (p == 0) ? qo : (p == 1) ? ko : vo;
        #pragma unroll
        for (int r = 0; r < 7; r++) {
            bf162 t; t.x = f2b(acc0[r]); t.y = f2b(acc1[r]);
            *(bf162*)(dst + (size_t)wb * kWinElems + (size_t)(n0 + r) * kC + co) = t;
        }
    }
}

// ---------------------------------------------------------------------------
// K2: attention per (window, head). Writes output back over the q buffer
// (each block touches only its own disjoint [wb, :, head*32:+32] slice).
__global__ __launch_bounds__(256) void k_attn(
    bf16* __restrict__ qbuf, const bf16* __restrict__ kbuf,
    const bf16* __restrict__ vbuf, const float* __restrict__ rpb)
{
    __shared__ float qs[kN][kHD + 1], ks[kN][kHD + 1], vs[kN][kHD + 1];
    __shared__ float S[kN][kN + 1];
    const int wb = blockIdx.x, head = blockIdx.y;
    const int tid = threadIdx.x;
    const size_t base = (size_t)wb * kWinElems + head * kHD;
    for (int i = tid; i < kN * kHD; i += 256) {
        const int n = i >> 5, d = i & 31;
        qs[n][d] = b2f(qbuf[base + (size_t)n * kC + d]);
        ks[n][d] = b2f(kbuf[base + (size_t)n * kC + d]);
        vs[n][d] = b2f(vbuf[base + (size_t)n * kC + d]);
    }
    __syncthreads();
    for (int i = tid; i < kN * kN; i += 256) {
        const int n = i / 49, m = i % 49;
        float acc = 0.f;
        #pragma unroll
        for (int d = 0; d < kHD; d++) acc += qs[n][d] * ks[m][d];
        const int ry = n / 7 - m / 7 + 6, rx = n % 7 - m % 7 + 6;
        S[n][m] = acc * kScale + rpb[(ry * 13 + rx) * kHeads + head];
    }
    __syncthreads();
    if (tid < kN) {
        float mx = -1e30f;
        for (int m = 0; m < kN; m++) mx = fmaxf(mx, S[tid][m]);
        float sum = 0.f;
        for (int m = 0; m < kN; m++) { const float e = __expf(S[tid][m] - mx); S[tid][m] = e; sum += e; }
        const float inv = 1.f / sum;
        for (int m = 0; m < kN; m++) S[tid][m] *= inv;
    }
    __syncthreads();
    for (int i = tid; i < kN * kHD; i += 256) {
        const int n = i >> 5, d = i & 31;
        float acc = 0.f;
        for (int m = 0; m < kN; m++) acc += S[n][m] * vs[m][d];
        qbuf[base + (size_t)n * kC + d] = f2b(acc);
    }
}

// ---------------------------------------------------------------------------
// K3: output projection + window reverse + residual. xo -> d_out (fp32).
__global__ __launch_bounds__(256) void k_proj(
    const bf16* __restrict__ ao, const float* __restrict__ pw,
    const float* __restrict__ pb, const float* __restrict__ x,
    float* __restrict__ out)
{
    __shared__ float a[kN][kC + 1];
    const int wb = blockIdx.x;
    const int b = wb >> 8, wy = (wb >> 4) & 15, wx = wb & 15;
    const int tid = threadIdx.x;
    for (int i = tid; i < kWinElems; i += 256)
        a[i >> 7][i & 127] = b2f(ao[(size_t)wb * kWinElems + i]);
    __syncthreads();
    for (int task = tid; task < 448; task += 256) {   // 7 tiles x 64 co-pairs
        const int tile = task / 64, co = (task & 63) * 2;
        const int n0 = tile * 7;
        const float4* w0 = (const float4*)(pw + (size_t)co * kC);
        const float4* w1 = (const float4*)(pw + (size_t)(co + 1) * kC);
        float acc0[7], acc1[7];
        const float bi0 = pb[co], bi1 = pb[co + 1];
        #pragma unroll
        for (int r = 0; r < 7; r++) { acc0[r] = bi0; acc1[r] = bi1; }
        for (int ci = 0; ci < 32; ci++) {
            const float4 wa = w0[ci];
            const float4 wbv = w1[ci];
            #pragma unroll
            for (int r = 0; r < 7; r++) {
                const float s0 = a[n0 + r][4 * ci],     s1 = a[n0 + r][4 * ci + 1];
                const float s2 = a[n0 + r][4 * ci + 2], s3 = a[n0 + r][4 * ci + 3];
                acc0[r] += wa.x * s0 + wa.y * s1 + wa.z * s2 + wa.w * s3;
                acc1[r] += wbv.x * s0 + wbv.y * s1 + wbv.z * s2 + wbv.w * s3;
            }
        }
        #pragma unroll
        for (int r = 0; r < 7; r++) {
            const int n = n0 + r;
            const size_t g = ((size_t)b * kL + (size_t)(wy * 7 + n / 7) * kW
                             + (wx * 7 + n % 7)) * kC + co;
            const float2 xres = *(const float2*)(x + g);
            float2 t;
            t.x = acc0[r] + xres.x;
            t.y = acc1[r] + xres.y;
            *(float2*)(out + g) = t;
        }
    }
}

// ---------------------------------------------------------------------------
// K4: LN2 + fc1 + exact GELU + fc2 + residual, in-place on d_out (fp32).
// 16 rows per block; each fc1 weight load feeds 16 row-accumulators.
__global__ __launch_bounds__(256) void k_mlp(
    float* __restrict__ out,
    const float* __restrict__ g2, const float* __restrict__ b2v,
    const float* __restrict__ w1, const float* __restrict__ bb1,
    const float* __restrict__ w2, const float* __restrict__ bb2)
{
    __shared__ float ln_s[16][kC + 1];
    __shared__ float h_s[16][kMLP + 1];
    const int tid = threadIdx.x, wave = tid >> 6, lane = tid & 63;
    const size_t row0 = (size_t)blockIdx.x * 16;
    const int c0 = lane * 2, c1 = c0 + 1;
    for (int n = wave; n < 16; n += 4) {
        const size_t r = (row0 + n) * kC;
        const float2 xv = *(const float2*)(out + r + c0);
        float s = xv.x + xv.y, q = xv.x * xv.x + xv.y * xv.y;
        #pragma unroll
        for (int off = 32; off > 0; off >>= 1) { s += __shfl_xor(s, off); q += __shfl_xor(q, off); }
        const float mu = s * (1.f / kC), iv = rsqrtf(q * (1.f / kC) - mu * mu + kEps);
        ln_s[n][c0] = (xv.x - mu) * iv * g2[c0] + b2v[c0];
        ln_s[n][c1] = (xv.y - mu) * iv * g2[c1] + b2v[c1];
    }
    __syncthreads();
    // fc1 + GELU: each thread owns hidden units j = tid and tid + 256.
    for (int jj = 0; jj < 2; jj++) {
        const int j = tid + jj * 256;
        const float4* wr = (const float4*)(w1 + (size_t)j * kC);
        float acc[16];
        const float bj = bb1[j];
        #pragma unroll
        for (int r = 0; r < 16; r++) acc[r] = bj;
        for (int ci = 0; ci < 32; ci++) {
            const float4 wf = wr[ci];
            #pragma unroll
            for (int r = 0; r < 16; r++)
                acc[r] += wf.x * ln_s[r][4 * ci]     + wf.y * ln_s[r][4 * ci + 1]
                        + wf.z * ln_s[r][4 * ci + 2] + wf.w * ln_s[r][4 * ci + 3];
        }
        #pragma unroll
        for (int r = 0; r < 16; r++) {
            const float aa = acc[r];
            h_s[r][j] = 0.5f * aa * (1.f + erff(aa * 0.70710678118f));  // exact gelu
        }
    }
    __syncthreads();
    // fc2: thread owns output col c for 8 rows.
    const int c = tid & 127, rh = tid >> 7;
    const float4* wr = (const float4*)(w2 + (size_t)c * kMLP);
    float acc[8];
    const float bc = bb2[c];
    #pragma unroll
    for (int r = 0; r < 8; r++) acc[r] = bc;
    for (int j = 0; j < 128; j++) {
        const float4 wf = wr[j];
        #pragma unroll
        for (int r = 0; r < 8; r++)
            acc[r] += wf.x * h_s[rh * 8 + r][4 * j]     + wf.y * h_s[rh * 8 + r][4 * j + 1]
                    + wf.z * h_s[rh * 8 + r][4 * j + 2] + wf.w * h_s[rh * 8 + r][4 * j + 3];
    }
    #pragma unroll
    for (int r = 0; r < 8; r++) {
        const size_t idx = (row0 + rh * 8 + r) * kC + c;
        out[idx] = out[idx] + acc[r];
    }
}

// ---------------------------------------------------------------------------
extern "C" void kernel_launch(void* const* d_in, const int* in_sizes, int n_in,
                              void* d_out, int out_size, void* d_ws, size_t ws_size,
                              hipStream_t stream) {
    (void)in_sizes; (void)n_in; (void)out_size; (void)ws_size;
    const float* x      = (const float*)d_in[0];
    const float* v      = (const float*)d_in[1];
    const float* n1g    = (const float*)d_in[2];
    const float* n1b    = (const float*)d_in[3];
    const float* nvg    = (const float*)d_in[4];
    const float* nvb    = (const float*)d_in[5];
    const float* q_w    = (const float*)d_in[6];
    const float* q_b    = (const float*)d_in[7];
    const float* kv_w   = (const float*)d_in[8];
    const float* kv_b   = (const float*)d_in[9];
    const float* rpb    = (const float*)d_in[10];
    const float* proj_w = (const float*)d_in[11];
    const float* proj_b = (const float*)d_in[12];
    const float* n2g    = (const float*)d_in[13];
    const float* n2b    = (const float*)d_in[14];
    const float* fc1_w  = (const float*)d_in[15];
    const float* fc1_b  = (const float*)d_in[16];
    const float* fc2_w  = (const float*)d_in[17];
    const float* fc2_b  = (const float*)d_in[18];
    // d_in[19], d_in[20] = H, W (int, constants 112/112)

    const size_t winTot = (size_t)4096 * kWinElems;   // 25,690,112 elems
    bf16* qbuf = (bf16*)d_ws;
    bf16* kbuf = qbuf + winTot;
    bf16* vbuf = kbuf + winTot;   // total ws use: 3 * 49 MB = 147 MB
    float* outb = (float*)d_out;

    k_ln_qkv<<<4096, 256, 0, stream>>>(x, v, n1g, n1b, nvg, nvb,
                                       q_w, q_b, kv_w, kv_b, qbuf, kbuf, vbuf);
    k_attn<<<dim3(4096, 4), 256, 0, stream>>>(qbuf, kbuf, vbuf, rpb);
    k_proj<<<4096, 256, 0, stream>>>(qbuf, proj_w, proj_b, x, outb);
    k_mlp<<<12544, 256, 0, stream>>>(outb, n2g, n2b, fc1_w, fc1_b, fc2_w, fc2_b);
}

// Round 3
// 1903.463 us; speedup vs baseline: 1.6384x; 1.6384x over previous
//
#include <hip/hip_runtime.h>
#include <hip/hip_bf16.h>
#include <math.h>

typedef __hip_bfloat16 bf16;
typedef __hip_bfloat162 bf162;
typedef __attribute__((ext_vector_type(8))) short bf16x8;   // MFMA A/B frag (4 VGPRs)
typedef __attribute__((ext_vector_type(4))) short short4v;  // 8B LDS store
typedef __attribute__((ext_vector_type(4))) float f32x4;    // MFMA C/D frag

__device__ __forceinline__ float b2f(bf16 x){ return __bfloat162float(x); }
__device__ __forceinline__ bf16  f2b(float x){ return __float2bfloat16(x); }
__device__ __forceinline__ short f2bs(float x){ bf16 h = __float2bfloat16(x); return *(short*)&h; }

constexpr int kH = 112, kW = 112, kC = 128, kHeads = 4, kWS = 7;
constexpr int kN = 49, kHD = 32, kL = kH * kW;      // L = 12544
constexpr int kWinElems = kN * kC;                  // 6272
constexpr int kMLP = 512;
constexpr float kEps = 1e-5f;
constexpr float kScale = 0.17677669529663687f;      // 1/sqrt(32)

// ---------------------------------------------------------------------------
// K0: convert fc1_w / fc2_w fp32 -> bf16 (once per launch; L2-resident after).
__global__ __launch_bounds__(256) void k_cvt(
    const float* __restrict__ s1, const float* __restrict__ s2,
    short* __restrict__ d1, short* __restrict__ d2)
{
    const int i = blockIdx.x * 256 + threadIdx.x;   // 131072 total
    if (i < 65536) d1[i] = f2bs(s1[i]);
    else           d2[i - 65536] = f2bs(s2[i - 65536]);
}

// ---------------------------------------------------------------------------
// K1: LN(x), LN(v) + window partition + Q/K/V projection. fp32 in, bf16 out.
__global__ __launch_bounds__(256) void k_ln_qkv(
    const float* __restrict__ x, const float* __restrict__ v,
    const float* __restrict__ n1g, const float* __restrict__ n1b,
    const float* __restrict__ nvg, const float* __restrict__ nvb,
    const float* __restrict__ qw, const float* __restrict__ qb,
    const float* __restrict__ kvw, const float* __restrict__ kvb,
    bf16* __restrict__ qo, bf16* __restrict__ ko, bf16* __restrict__ vo)
{
    __shared__ float xn[kN][kC + 1];
    __shared__ float vn[kN][kC + 1];
    const int wb = blockIdx.x;
    const int b = wb >> 8, wy = (wb >> 4) & 15, wx = wb & 15;
    const int tid = threadIdx.x, wave = tid >> 6, lane = tid & 63;
    const int c0 = lane * 2, c1 = c0 + 1;

    for (int n = wave; n < kN; n += 4) {
        const int hh = wy * kWS + n / 7, ww = wx * kWS + n % 7;
        const size_t r = ((size_t)b * kL + (size_t)hh * kW + ww) * kC;
        const float2 xv = *(const float2*)(x + r + c0);
        const float2 vv = *(const float2*)(v + r + c0);
        float sx = xv.x + xv.y, qx = xv.x * xv.x + xv.y * xv.y;
        float sv = vv.x + vv.y, qv = vv.x * vv.x + vv.y * vv.y;
        #pragma unroll
        for (int off = 32; off > 0; off >>= 1) {
            sx += __shfl_xor(sx, off); qx += __shfl_xor(qx, off);
            sv += __shfl_xor(sv, off); qv += __shfl_xor(qv, off);
        }
        const float mux = sx * (1.f / kC);
        const float ivx = rsqrtf(qx * (1.f / kC) - mux * mux + kEps);
        const float muv = sv * (1.f / kC);
        const float ivv = rsqrtf(qv * (1.f / kC) - muv * muv + kEps);
        xn[n][c0] = (xv.x - mux) * ivx * n1g[c0] + n1b[c0];
        xn[n][c1] = (xv.y - mux) * ivx * n1g[c1] + n1b[c1];
        vn[n][c0] = (vv.x - muv) * ivv * nvg[c0] + nvb[c0];
        vn[n][c1] = (vv.y - muv) * ivv * nvg[c1] + nvb[c1];
    }
    __syncthreads();

    for (int task = tid; task < 1344; task += 256) {
        const int tile = task / 192, rem = task % 192;
        const int p = rem >> 6, co = (rem & 63) * 2;
        const int n0 = tile * 7;
        const float (*src)[kC + 1] = (p == 0) ? xn : vn;
        const float* w = (p == 0) ? qw : kvw;
        const int row = (p == 2) ? (128 + co) : co;
        const float4* w0 = (const float4*)(w + (size_t)row * kC);
        const float4* w1 = (const float4*)(w + (size_t)(row + 1) * kC);
        const float* bias = (p == 0) ? qb : kvb;
        float acc0[7], acc1[7];
        const float bi0 = bias[row], bi1 = bias[row + 1];
        #pragma unroll
        for (int r = 0; r < 7; r++) { acc0[r] = bi0; acc1[r] = bi1; }
        for (int ci = 0; ci < 32; ci++) {
            const float4 wa = w0[ci];
            const float4 wbv = w1[ci];
            #pragma unroll
            for (int r = 0; r < 7; r++) {
                const float s0 = src[n0 + r][4 * ci],     s1 = src[n0 + r][4 * ci + 1];
                const float s2 = src[n0 + r][4 * ci + 2], s3 = src[n0 + r][4 * ci + 3];
                acc0[r] += wa.x * s0 + wa.y * s1 + wa.z * s2 + wa.w * s3;
                acc1[r] += wbv.x * s0 + wbv.y * s1 + wbv.z * s2 + wbv.w * s3;
            }
        }
        bf16* dst = (p == 0) ? qo : (p == 1) ? ko : vo;
        #pragma unroll
        for (int r = 0; r < 7; r++) {
            bf162 t; t.x = f2b(acc0[r]); t.y = f2b(acc1[r]);
            *(bf162*)(dst + (size_t)wb * kWinElems + (size_t)(n0 + r) * kC + co) = t;
        }
    }
}

// ---------------------------------------------------------------------------
// K2: attention per (window, head). Writes back over the q buffer.
__global__ __launch_bounds__(256) void k_attn(
    bf16* __restrict__ qbuf, const bf16* __restrict__ kbuf,
    const bf16* __restrict__ vbuf, const float* __restrict__ rpb)
{
    __shared__ float qs[kN][kHD + 1], ks[kN][kHD + 1], vs[kN][kHD + 1];
    __shared__ float S[kN][kN + 1];
    const int wb = blockIdx.x, head = blockIdx.y;
    const int tid = threadIdx.x;
    const size_t base = (size_t)wb * kWinElems + head * kHD;
    for (int i = tid; i < kN * kHD; i += 256) {
        const int n = i >> 5, d = i & 31;
        qs[n][d] = b2f(qbuf[base + (size_t)n * kC + d]);
        ks[n][d] = b2f(kbuf[base + (size_t)n * kC + d]);
        vs[n][d] = b2f(vbuf[base + (size_t)n * kC + d]);
    }
    __syncthreads();
    for (int i = tid; i < kN * kN; i += 256) {
        const int n = i / 49, m = i % 49;
        float acc = 0.f;
        #pragma unroll
        for (int d = 0; d < kHD; d++) acc += qs[n][d] * ks[m][d];
        const int ry = n / 7 - m / 7 + 6, rx = n % 7 - m % 7 + 6;
        S[n][m] = acc * kScale + rpb[(ry * 13 + rx) * kHeads + head];
    }
    __syncthreads();
    if (tid < kN) {
        float mx = -1e30f;
        for (int m = 0; m < kN; m++) mx = fmaxf(mx, S[tid][m]);
        float sum = 0.f;
        for (int m = 0; m < kN; m++) { const float e = __expf(S[tid][m] - mx); S[tid][m] = e; sum += e; }
        const float inv = 1.f / sum;
        for (int m = 0; m < kN; m++) S[tid][m] *= inv;
    }
    __syncthreads();
    for (int i = tid; i < kN * kHD; i += 256) {
        const int n = i >> 5, d = i & 31;
        float acc = 0.f;
        for (int m = 0; m < kN; m++) acc += S[n][m] * vs[m][d];
        qbuf[base + (size_t)n * kC + d] = f2b(acc);
    }
}

// ---------------------------------------------------------------------------
// K3: output projection + window reverse + residual. xo -> d_out (fp32).
__global__ __launch_bounds__(256) void k_proj(
    const bf16* __restrict__ ao, const float* __restrict__ pw,
    const float* __restrict__ pb, const float* __restrict__ x,
    float* __restrict__ out)
{
    __shared__ float a[kN][kC + 1];
    const int wb = blockIdx.x;
    const int b = wb >> 8, wy = (wb >> 4) & 15, wx = wb & 15;
    const int tid = threadIdx.x;
    for (int i = tid; i < kWinElems; i += 256)
        a[i >> 7][i & 127] = b2f(ao[(size_t)wb * kWinElems + i]);
    __syncthreads();
    for (int task = tid; task < 448; task += 256) {
        const int tile = task / 64, co = (task & 63) * 2;
        const int n0 = tile * 7;
        const float4* w0 = (const float4*)(pw + (size_t)co * kC);
        const float4* w1 = (const float4*)(pw + (size_t)(co + 1) * kC);
        float acc0[7], acc1[7];
        const float bi0 = pb[co], bi1 = pb[co + 1];
        #pragma unroll
        for (int r = 0; r < 7; r++) { acc0[r] = bi0; acc1[r] = bi1; }
        for (int ci = 0; ci < 32; ci++) {
            const float4 wa = w0[ci];
            const float4 wbv = w1[ci];
            #pragma unroll
            for (int r = 0; r < 7; r++) {
                const float s0 = a[n0 + r][4 * ci],     s1 = a[n0 + r][4 * ci + 1];
                const float s2 = a[n0 + r][4 * ci + 2], s3 = a[n0 + r][4 * ci + 3];
                acc0[r] += wa.x * s0 + wa.y * s1 + wa.z * s2 + wa.w * s3;
                acc1[r] += wbv.x * s0 + wbv.y * s1 + wbv.z * s2 + wbv.w * s3;
            }
        }
        #pragma unroll
        for (int r = 0; r < 7; r++) {
            const int n = n0 + r;
            const size_t g = ((size_t)b * kL + (size_t)(wy * 7 + n / 7) * kW
                             + (wx * 7 + n % 7)) * kC + co;
            const float2 xres = *(const float2*)(x + g);
            float2 t;
            t.x = acc0[r] + xres.x;
            t.y = acc1[r] + xres.y;
            *(float2*)(out + g) = t;
        }
    }
}

// ---------------------------------------------------------------------------
// K4 (MFMA): LN2 + fc1 + exact GELU + fc2 + residual, in-place on d_out.
// 32 rows/block, 4 waves. Swapped-operand MFMA (weights=A, acts=B) so the
// C/D layout yields 4 consecutive hidden/channel indices per lane:
//   fc1 out -> ds_write_b64 packed bf16, fc2 out -> float4 global store.
constexpr int kMT = 32;       // rows per block
constexpr int kAP = 136;      // A_s row stride (bf16): 272B = 17*16, 2-way banks
constexpr int kHP = 520;      // H_s row stride (bf16): 1040B = 65*16

__global__ __launch_bounds__(256) void k_mlp_mfma(
    float* __restrict__ out,
    const float* __restrict__ g2, const float* __restrict__ b2v,
    const short* __restrict__ w1b, const float* __restrict__ bb1,
    const short* __restrict__ w2b, const float* __restrict__ bb2)
{
    __shared__ short A_s[kMT * kAP];   // LN output, bf16  (8.7 KB)
    __shared__ short H_s[kMT * kHP];   // hidden, bf16     (33.3 KB)
    const int tid = threadIdx.x, wave = tid >> 6, lane = tid & 63;
    const int quad = lane >> 4, l16 = lane & 15;
    const size_t row0 = (size_t)blockIdx.x * kMT;
    const int c0 = lane * 2;

    // ---- LN2 -> A_s (bf16) ----
    for (int n = wave; n < kMT; n += 4) {
        const float2 xv = *(const float2*)(out + (row0 + n) * kC + c0);
        float s = xv.x + xv.y, q = xv.x * xv.x + xv.y * xv.y;
        #pragma unroll
        for (int off = 32; off > 0; off >>= 1) { s += __shfl_xor(s, off); q += __shfl_xor(q, off); }
        const float mu = s * (1.f / kC), iv = rsqrtf(q * (1.f / kC) - mu * mu + kEps);
        A_s[n * kAP + c0]     = f2bs((xv.x - mu) * iv * g2[c0] + b2v[c0]);
        A_s[n * kAP + c0 + 1] = f2bs((xv.y - mu) * iv * g2[c0 + 1] + b2v[c0 + 1]);
    }
    __syncthreads();

    // ---- fc1: D1[n][m] = sum_k W1[n][k]*A[m][k].  Wave: 8 n-tiles x 2 m-tiles.
    f32x4 acc[8][2];
    #pragma unroll
    for (int t = 0; t < 8; t++) {
        const int nb = (wave * 8 + t) * 16 + quad * 4;
        f32x4 bi = { bb1[nb], bb1[nb + 1], bb1[nb + 2], bb1[nb + 3] };
        acc[t][0] = bi; acc[t][1] = bi;
    }
    bf16x8 bfrag[2][4];   // activation fragments, reused across all n-tiles
    #pragma unroll
    for (int mt = 0; mt < 2; mt++)
        #pragma unroll
        for (int ks = 0; ks < 4; ks++)
            bfrag[mt][ks] = *(const bf16x8*)&A_s[(mt * 16 + l16) * kAP + ks * 32 + quad * 8];
    #pragma unroll
    for (int t = 0; t < 8; t++) {
        const int nt = wave * 8 + t;
        #pragma unroll
        for (int ks = 0; ks < 4; ks++) {
            const bf16x8 af = *(const bf16x8*)(w1b + (size_t)(nt * 16 + l16) * kC + ks * 32 + quad * 8);
            acc[t][0] = __builtin_amdgcn_mfma_f32_16x16x32_bf16(af, bfrag[0][ks], acc[t][0], 0, 0, 0);
            acc[t][1] = __builtin_amdgcn_mfma_f32_16x16x32_bf16(af, bfrag[1][ks], acc[t][1], 0, 0, 0);
        }
    }
    // GELU (exact) + pack 4 consecutive hidden -> ds_write_b64
    #pragma unroll
    for (int t = 0; t < 8; t++) {
        const int nb = (wave * 8 + t) * 16 + quad * 4;
        #pragma unroll
        for (int mt = 0; mt < 2; mt++) {
            short4v p;
            #pragma unroll
            for (int i = 0; i < 4; i++) {
                const float a = acc[t][mt][i];
                p[i] = f2bs(0.5f * a * (1.f + erff(a * 0.70710678118f)));
            }
            *(short4v*)&H_s[(mt * 16 + l16) * kHP + nb] = p;
        }
    }
    __syncthreads();

    // ---- fc2: D2[c][m] = sum_k W2[c][k]*H[m][k].  Wave: mtile = w&1, 4 c-tiles.
    const int mtile = wave & 1, ct0 = (wave >> 1) * 4;
    f32x4 acc2[4];
    #pragma unroll
    for (int t = 0; t < 4; t++) {
        const int cb = (ct0 + t) * 16 + quad * 4;
        acc2[t] = (f32x4){ bb2[cb], bb2[cb + 1], bb2[cb + 2], bb2[cb + 3] };
    }
    #pragma unroll
    for (int ks = 0; ks < 16; ks++) {
        const bf16x8 hf = *(const bf16x8*)&H_s[(mtile * 16 + l16) * kHP + ks * 32 + quad * 8];
        #pragma unroll
        for (int t = 0; t < 4; t++) {
            const bf16x8 wf = *(const bf16x8*)(w2b + (size_t)((ct0 + t) * 16 + l16) * kMLP + ks * 32 + quad * 8);
            acc2[t] = __builtin_amdgcn_mfma_f32_16x16x32_bf16(wf, hf, acc2[t], 0, 0, 0);
        }
    }
    // residual + store: lane owns row m, 4 consecutive channels per tile
    const size_t m = row0 + mtile * 16 + l16;
    #pragma unroll
    for (int t = 0; t < 4; t++) {
        const int cb = (ct0 + t) * 16 + quad * 4;
        float4 res = *(const float4*)(out + m * kC + cb);
        res.x += acc2[t][0]; res.y += acc2[t][1];
        res.z += acc2[t][2]; res.w += acc2[t][3];
        *(float4*)(out + m * kC + cb) = res;
    }
}

// ---------------------------------------------------------------------------
extern "C" void kernel_launch(void* const* d_in, const int* in_sizes, int n_in,
                              void* d_out, int out_size, void* d_ws, size_t ws_size,
                              hipStream_t stream) {
    (void)in_sizes; (void)n_in; (void)out_size; (void)ws_size;
    const float* x      = (const float*)d_in[0];
    const float* v      = (const float*)d_in[1];
    const float* n1g    = (const float*)d_in[2];
    const float* n1b    = (const float*)d_in[3];
    const float* nvg    = (const float*)d_in[4];
    const float* nvb    = (const float*)d_in[5];
    const float* q_w    = (const float*)d_in[6];
    const float* q_b    = (const float*)d_in[7];
    const float* kv_w   = (const float*)d_in[8];
    const float* kv_b   = (const float*)d_in[9];
    const float* rpb    = (const float*)d_in[10];
    const float* proj_w = (const float*)d_in[11];
    const float* proj_b = (const float*)d_in[12];
    const float* n2g    = (const float*)d_in[13];
    const float* n2b    = (const float*)d_in[14];
    const float* fc1_w  = (const float*)d_in[15];
    const float* fc1_b  = (const float*)d_in[16];
    const float* fc2_w  = (const float*)d_in[17];
    const float* fc2_b  = (const float*)d_in[18];

    const size_t winTot = (size_t)4096 * kWinElems;   // 25,690,112 elems
    bf16* qbuf = (bf16*)d_ws;
    bf16* kbuf = qbuf + winTot;
    bf16* vbuf = kbuf + winTot;                        // 147 MB
    short* w1b = (short*)(vbuf + winTot);              // 128 KB (512x128 bf16)
    short* w2b = w1b + 512 * 128;                      // 128 KB (128x512 bf16)
    float* outb = (float*)d_out;

    k_cvt<<<512, 256, 0, stream>>>(fc1_w, fc2_w, w1b, w2b);
    k_ln_qkv<<<4096, 256, 0, stream>>>(x, v, n1g, n1b, nvg, nvb,
                                       q_w, q_b, kv_w, kv_b, qbuf, kbuf, vbuf);
    k_attn<<<dim3(4096, 4), 256, 0, stream>>>(qbuf, kbuf, vbuf, rpb);
    k_proj<<<4096, 256, 0, stream>>>(qbuf, proj_w, proj_b, x, outb);
    k_mlp_mfma<<<6272, 256, 0, stream>>>(outb, n2g, n2b, w1b, fc1_b, w2b, fc2_b);
}

// Round 4
// 1081.142 us; speedup vs baseline: 2.8845x; 1.7606x over previous
//
#include <hip/hip_runtime.h>
#include <hip/hip_bf16.h>
#include <math.h>

typedef __hip_bfloat16 bf16;
typedef __hip_bfloat162 bf162;
typedef __attribute__((ext_vector_type(8))) short bf16x8;   // MFMA A/B frag (4 VGPRs)
typedef __attribute__((ext_vector_type(4))) short short4v;  // 8B store
typedef __attribute__((ext_vector_type(4))) float f32x4;    // MFMA C/D frag

__device__ __forceinline__ float b2f(bf16 x){ return __bfloat162float(x); }
__device__ __forceinline__ bf16  f2b(float x){ return __float2bfloat16(x); }
__device__ __forceinline__ short f2bs(float x){ bf16 h = __float2bfloat16(x); return *(short*)&h; }

constexpr int kH = 112, kW = 112, kC = 128, kHeads = 4, kWS = 7;
constexpr int kN = 49, kHD = 32, kL = kH * kW;      // L = 12544
constexpr int kWinElems = kN * kC;                  // 6272
constexpr int kMLP = 512;
constexpr float kEps = 1e-5f;
constexpr float kScale = 0.17677669529663687f;      // 1/sqrt(32)
constexpr int kAP = 136;      // LDS row stride (bf16): 272B = 17*16
constexpr int kHP = 520;      // MLP hidden stride

// ---------------------------------------------------------------------------
// K0: convert all weight matrices fp32 -> bf16 into one ws arena.
// Layout: [qwb 16384 | kvwb 32768 | pwb 16384 | w1b 65536 | w2b 65536]
__global__ __launch_bounds__(256) void k_cvt(
    const float* __restrict__ qw, const float* __restrict__ kvw,
    const float* __restrict__ pw, const float* __restrict__ w1,
    const float* __restrict__ w2, short* __restrict__ dst)
{
    const int i = blockIdx.x * 256 + threadIdx.x;   // 196608 total
    float val;
    if (i < 16384)       val = qw[i];
    else if (i < 49152)  val = kvw[i - 16384];
    else if (i < 65536)  val = pw[i - 49152];
    else if (i < 131072) val = w1[i - 65536];
    else                 val = w2[i - 131072];
    dst[i] = f2bs(val);
}

// ---------------------------------------------------------------------------
// K1 (MFMA): LN(x), LN(v) + Q/K/V projection + window-partition scatter.
// 32 consecutive (b,l) rows per block; weights = A operand, acts = B operand.
// D layout: col(lane&15)=row m, row(quad*4+i)=out channel -> 8B bf16x4 stores.
__global__ __launch_bounds__(256) void k_ln_qkv_mfma(
    const float* __restrict__ x, const float* __restrict__ v,
    const float* __restrict__ n1g, const float* __restrict__ n1b,
    const float* __restrict__ nvg, const float* __restrict__ nvb,
    const short* __restrict__ qwb, const float* __restrict__ qb,
    const short* __restrict__ kvwb, const float* __restrict__ kvb,
    bf16* __restrict__ qo, bf16* __restrict__ ko, bf16* __restrict__ vo)
{
    __shared__ short Xs[32 * kAP], Vs[32 * kAP];
    const int tid = threadIdx.x, wave = tid >> 6, lane = tid & 63;
    const int quad = lane >> 4, l16 = lane & 15;
    const int row0 = blockIdx.x * 32;
    const int c0 = lane * 2;

    // ---- LN(x), LN(v) -> LDS bf16 ----
    for (int n = wave; n < 32; n += 4) {
        const size_t r = (size_t)(row0 + n) * kC;
        const float2 xv = *(const float2*)(x + r + c0);
        const float2 vv = *(const float2*)(v + r + c0);
        float sx = xv.x + xv.y, qx = xv.x * xv.x + xv.y * xv.y;
        float sv = vv.x + vv.y, qv = vv.x * vv.x + vv.y * vv.y;
        #pragma unroll
        for (int off = 32; off > 0; off >>= 1) {
            sx += __shfl_xor(sx, off); qx += __shfl_xor(qx, off);
            sv += __shfl_xor(sv, off); qv += __shfl_xor(qv, off);
        }
        const float mux = sx * (1.f / kC);
        const float ivx = rsqrtf(qx * (1.f / kC) - mux * mux + kEps);
        const float muv = sv * (1.f / kC);
        const float ivv = rsqrtf(qv * (1.f / kC) - muv * muv + kEps);
        Xs[n * kAP + c0]     = f2bs((xv.x - mux) * ivx * n1g[c0] + n1b[c0]);
        Xs[n * kAP + c0 + 1] = f2bs((xv.y - mux) * ivx * n1g[c0 + 1] + n1b[c0 + 1]);
        Vs[n * kAP + c0]     = f2bs((vv.x - muv) * ivv * nvg[c0] + nvb[c0]);
        Vs[n * kAP + c0 + 1] = f2bs((vv.y - muv) * ivv * nvg[c0 + 1] + nvb[c0 + 1]);
    }
    __syncthreads();

    // ---- windowed scatter offsets for this lane's two m-tile rows ----
    int woff[2];
    #pragma unroll
    for (int mt = 0; mt < 2; mt++) {
        const int gr = row0 + mt * 16 + l16;
        const int b = gr / kL, l = gr - b * kL;
        const int h = l / kW, w_ = l - h * kW;
        woff[mt] = ((b << 8) + (h / 7) * 16 + (w_ / 7)) * kWinElems
                 + ((h % 7) * 7 + (w_ % 7)) * kC;
    }

    // ---- preload activation B-fragments ----
    bf16x8 xf[2][4], vf[2][4];
    #pragma unroll
    for (int mt = 0; mt < 2; mt++)
        #pragma unroll
        for (int ks = 0; ks < 4; ks++) {
            xf[mt][ks] = *(const bf16x8*)&Xs[(mt * 16 + l16) * kAP + ks * 32 + quad * 8];
            vf[mt][ks] = *(const bf16x8*)&Vs[(mt * 16 + l16) * kAP + ks * 32 + quad * 8];
        }

    // ---- 24 out-channel tiles (q:0-7, k:8-15, v:16-23), 6 per wave ----
    #pragma unroll
    for (int j = 0; j < 6; j++) {
        const int nt = wave * 6 + j;
        const bool isq = (nt < 8);
        const short* wmat = isq ? qwb : kvwb;
        const int wr0 = (isq ? nt : nt - 8) * 16;
        const float* bias = isq ? qb : kvb;
        const int bidx = wr0 + quad * 4;
        f32x4 a0 = { bias[bidx], bias[bidx + 1], bias[bidx + 2], bias[bidx + 3] };
        f32x4 a1 = a0;
        if (isq) {
            #pragma unroll
            for (int ks = 0; ks < 4; ks++) {
                const bf16x8 af = *(const bf16x8*)(wmat + (size_t)(wr0 + l16) * kC + ks * 32 + quad * 8);
                a0 = __builtin_amdgcn_mfma_f32_16x16x32_bf16(af, xf[0][ks], a0, 0, 0, 0);
                a1 = __builtin_amdgcn_mfma_f32_16x16x32_bf16(af, xf[1][ks], a1, 0, 0, 0);
            }
        } else {
            #pragma unroll
            for (int ks = 0; ks < 4; ks++) {
                const bf16x8 af = *(const bf16x8*)(wmat + (size_t)(wr0 + l16) * kC + ks * 32 + quad * 8);
                a0 = __builtin_amdgcn_mfma_f32_16x16x32_bf16(af, vf[0][ks], a0, 0, 0, 0);
                a1 = __builtin_amdgcn_mfma_f32_16x16x32_bf16(af, vf[1][ks], a1, 0, 0, 0);
            }
        }
        bf16* dst = isq ? qo : (nt < 16 ? ko : vo);
        const int cb = (isq ? nt : (nt < 16 ? nt - 8 : nt - 16)) * 16 + quad * 4;
        short4v p0, p1;
        #pragma unroll
        for (int i = 0; i < 4; i++) { p0[i] = f2bs(a0[i]); p1[i] = f2bs(a1[i]); }
        *(short4v*)((short*)dst + (size_t)woff[0] + cb) = p0;
        *(short4v*)((short*)dst + (size_t)woff[1] + cb) = p1;
    }
}

// ---------------------------------------------------------------------------
// K2: attention per (window, head). Writes back over the q buffer.
__global__ __launch_bounds__(256) void k_attn(
    bf16* __restrict__ qbuf, const bf16* __restrict__ kbuf,
    const bf16* __restrict__ vbuf, const float* __restrict__ rpb)
{
    __shared__ float qs[kN][kHD + 1], ks[kN][kHD + 1], vs[kN][kHD + 1];
    __shared__ float S[kN][kN + 1];
    const int wb = blockIdx.x, head = blockIdx.y;
    const int tid = threadIdx.x;
    const size_t base = (size_t)wb * kWinElems + head * kHD;
    for (int i = tid; i < kN * kHD; i += 256) {
        const int n = i >> 5, d = i & 31;
        qs[n][d] = b2f(qbuf[base + (size_t)n * kC + d]);
        ks[n][d] = b2f(kbuf[base + (size_t)n * kC + d]);
        vs[n][d] = b2f(vbuf[base + (size_t)n * kC + d]);
    }
    __syncthreads();
    for (int i = tid; i < kN * kN; i += 256) {
        const int n = i / 49, m = i % 49;
        float acc = 0.f;
        #pragma unroll
        for (int d = 0; d < kHD; d++) acc += qs[n][d] * ks[m][d];
        const int ry = n / 7 - m / 7 + 6, rx = n % 7 - m % 7 + 6;
        S[n][m] = acc * kScale + rpb[(ry * 13 + rx) * kHeads + head];
    }
    __syncthreads();
    if (tid < kN) {
        float mx = -1e30f;
        for (int m = 0; m < kN; m++) mx = fmaxf(mx, S[tid][m]);
        float sum = 0.f;
        for (int m = 0; m < kN; m++) { const float e = __expf(S[tid][m] - mx); S[tid][m] = e; sum += e; }
        const float inv = 1.f / sum;
        for (int m = 0; m < kN; m++) S[tid][m] *= inv;
    }
    __syncthreads();
    for (int i = tid; i < kN * kHD; i += 256) {
        const int n = i >> 5, d = i & 31;
        float acc = 0.f;
        for (int m = 0; m < kN; m++) acc += S[n][m] * vs[m][d];
        qbuf[base + (size_t)n * kC + d] = f2b(acc);
    }
}

// ---------------------------------------------------------------------------
// K3 (MFMA): window-reverse gather + output projection + residual -> d_out.
__global__ __launch_bounds__(256) void k_proj_mfma(
    const bf16* __restrict__ ao, const short* __restrict__ pwb,
    const float* __restrict__ pb, const float* __restrict__ x,
    float* __restrict__ out)
{
    __shared__ short As[32 * kAP];
    const int tid = threadIdx.x, wave = tid >> 6, lane = tid & 63;
    const int quad = lane >> 4, l16 = lane & 15;
    const int row0 = blockIdx.x * 32;
    const int c0 = lane * 2;

    // gather windowed attn rows into LDS (bf16 passthrough)
    for (int n = wave; n < 32; n += 4) {
        const int gr = row0 + n;
        const int b = gr / kL, l = gr - b * kL;
        const int h = l / kW, w_ = l - h * kW;
        const size_t off = (size_t)(((b << 8) + (h / 7) * 16 + (w_ / 7))) * kWinElems
                         + ((h % 7) * 7 + (w_ % 7)) * kC;
        *(int*)&As[n * kAP + c0] = *(const int*)((const short*)ao + off + c0);
    }
    __syncthreads();

    bf16x8 bfrag[2][4];
    #pragma unroll
    for (int mt = 0; mt < 2; mt++)
        #pragma unroll
        for (int ks = 0; ks < 4; ks++)
            bfrag[mt][ks] = *(const bf16x8*)&As[(mt * 16 + l16) * kAP + ks * 32 + quad * 8];

    #pragma unroll
    for (int j = 0; j < 2; j++) {
        const int nt = wave * 2 + j;
        const int cb = nt * 16 + quad * 4;
        f32x4 a0 = { pb[cb], pb[cb + 1], pb[cb + 2], pb[cb + 3] };
        f32x4 a1 = a0;
        #pragma unroll
        for (int ks = 0; ks < 4; ks++) {
            const bf16x8 af = *(const bf16x8*)(pwb + (size_t)(nt * 16 + l16) * kC + ks * 32 + quad * 8);
            a0 = __builtin_amdgcn_mfma_f32_16x16x32_bf16(af, bfrag[0][ks], a0, 0, 0, 0);
            a1 = __builtin_amdgcn_mfma_f32_16x16x32_bf16(af, bfrag[1][ks], a1, 0, 0, 0);
        }
        #pragma unroll
        for (int mt = 0; mt < 2; mt++) {
            const size_t gr = row0 + mt * 16 + l16;
            float4 res = *(const float4*)(x + gr * kC + cb);
            const f32x4 a = mt ? a1 : a0;
            res.x += a[0]; res.y += a[1]; res.z += a[2]; res.w += a[3];
            *(float4*)(out + gr * kC + cb) = res;
        }
    }
}

// ---------------------------------------------------------------------------
// K4 (MFMA): LN2 + fc1 + exact GELU + fc2 + residual, in-place on d_out.
constexpr int kMT = 32;

__global__ __launch_bounds__(256) void k_mlp_mfma(
    float* __restrict__ out,
    const float* __restrict__ g2, const float* __restrict__ b2v,
    const short* __restrict__ w1b, const float* __restrict__ bb1,
    const short* __restrict__ w2b, const float* __restrict__ bb2)
{
    __shared__ short A_s[kMT * kAP];
    __shared__ short H_s[kMT * kHP];
    const int tid = threadIdx.x, wave = tid >> 6, lane = tid & 63;
    const int quad = lane >> 4, l16 = lane & 15;
    const size_t row0 = (size_t)blockIdx.x * kMT;
    const int c0 = lane * 2;

    for (int n = wave; n < kMT; n += 4) {
        const float2 xv = *(const float2*)(out + (row0 + n) * kC + c0);
        float s = xv.x + xv.y, q = xv.x * xv.x + xv.y * xv.y;
        #pragma unroll
        for (int off = 32; off > 0; off >>= 1) { s += __shfl_xor(s, off); q += __shfl_xor(q, off); }
        const float mu = s * (1.f / kC), iv = rsqrtf(q * (1.f / kC) - mu * mu + kEps);
        A_s[n * kAP + c0]     = f2bs((xv.x - mu) * iv * g2[c0] + b2v[c0]);
        A_s[n * kAP + c0 + 1] = f2bs((xv.y - mu) * iv * g2[c0 + 1] + b2v[c0 + 1]);
    }
    __syncthreads();

    f32x4 acc[8][2];
    #pragma unroll
    for (int t = 0; t < 8; t++) {
        const int nb = (wave * 8 + t) * 16 + quad * 4;
        f32x4 bi = { bb1[nb], bb1[nb + 1], bb1[nb + 2], bb1[nb + 3] };
        acc[t][0] = bi; acc[t][1] = bi;
    }
    bf16x8 bfrag[2][4];
    #pragma unroll
    for (int mt = 0; mt < 2; mt++)
        #pragma unroll
        for (int ks = 0; ks < 4; ks++)
            bfrag[mt][ks] = *(const bf16x8*)&A_s[(mt * 16 + l16) * kAP + ks * 32 + quad * 8];
    #pragma unroll
    for (int t = 0; t < 8; t++) {
        const int nt = wave * 8 + t;
        #pragma unroll
        for (int ks = 0; ks < 4; ks++) {
            const bf16x8 af = *(const bf16x8*)(w1b + (size_t)(nt * 16 + l16) * kC + ks * 32 + quad * 8);
            acc[t][0] = __builtin_amdgcn_mfma_f32_16x16x32_bf16(af, bfrag[0][ks], acc[t][0], 0, 0, 0);
            acc[t][1] = __builtin_amdgcn_mfma_f32_16x16x32_bf16(af, bfrag[1][ks], acc[t][1], 0, 0, 0);
        }
    }
    #pragma unroll
    for (int t = 0; t < 8; t++) {
        const int nb = (wave * 8 + t) * 16 + quad * 4;
        #pragma unroll
        for (int mt = 0; mt < 2; mt++) {
            short4v p;
            #pragma unroll
            for (int i = 0; i < 4; i++) {
                const float a = acc[t][mt][i];
                p[i] = f2bs(0.5f * a * (1.f + erff(a * 0.70710678118f)));
            }
            *(short4v*)&H_s[(mt * 16 + l16) * kHP + nb] = p;
        }
    }
    __syncthreads();

    const int mtile = wave & 1, ct0 = (wave >> 1) * 4;
    f32x4 acc2[4];
    #pragma unroll
    for (int t = 0; t < 4; t++) {
        const int cbv = (ct0 + t) * 16 + quad * 4;
        acc2[t] = (f32x4){ bb2[cbv], bb2[cbv + 1], bb2[cbv + 2], bb2[cbv + 3] };
    }
    #pragma unroll
    for (int ksv = 0; ksv < 16; ksv++) {
        const bf16x8 hf = *(const bf16x8*)&H_s[(mtile * 16 + l16) * kHP + ksv * 32 + quad * 8];
        #pragma unroll
        for (int t = 0; t < 4; t++) {
            const bf16x8 wf = *(const bf16x8*)(w2b + (size_t)((ct0 + t) * 16 + l16) * kMLP + ksv * 32 + quad * 8);
            acc2[t] = __builtin_amdgcn_mfma_f32_16x16x32_bf16(wf, hf, acc2[t], 0, 0, 0);
        }
    }
    const size_t m = row0 + mtile * 16 + l16;
    #pragma unroll
    for (int t = 0; t < 4; t++) {
        const int cbv = (ct0 + t) * 16 + quad * 4;
        float4 res = *(const float4*)(out + m * kC + cbv);
        res.x += acc2[t][0]; res.y += acc2[t][1];
        res.z += acc2[t][2]; res.w += acc2[t][3];
        *(float4*)(out + m * kC + cbv) = res;
    }
}

// ---------------------------------------------------------------------------
extern "C" void kernel_launch(void* const* d_in, const int* in_sizes, int n_in,
                              void* d_out, int out_size, void* d_ws, size_t ws_size,
                              hipStream_t stream) {
    (void)in_sizes; (void)n_in; (void)out_size; (void)ws_size;
    const float* x      = (const float*)d_in[0];
    const float* v      = (const float*)d_in[1];
    const float* n1g    = (const float*)d_in[2];
    const float* n1b    = (const float*)d_in[3];
    const float* nvg    = (const float*)d_in[4];
    const float* nvb    = (const float*)d_in[5];
    const float* q_w    = (const float*)d_in[6];
    const float* q_b    = (const float*)d_in[7];
    const float* kv_w   = (const float*)d_in[8];
    const float* kv_b   = (const float*)d_in[9];
    const float* rpb    = (const float*)d_in[10];
    const float* proj_w = (const float*)d_in[11];
    const float* proj_b = (const float*)d_in[12];
    const float* n2g    = (const float*)d_in[13];
    const float* n2b    = (const float*)d_in[14];
    const float* fc1_w  = (const float*)d_in[15];
    const float* fc1_b  = (const float*)d_in[16];
    const float* fc2_w  = (const float*)d_in[17];
    const float* fc2_b  = (const float*)d_in[18];

    const size_t winTot = (size_t)4096 * kWinElems;   // 25,690,112 elems
    bf16* qbuf = (bf16*)d_ws;
    bf16* kbuf = qbuf + winTot;
    bf16* vbuf = kbuf + winTot;                        // 154 MB
    short* wcvt = (short*)(vbuf + winTot);             // bf16 weight arena
    short* qwb  = wcvt;                                // 16384
    short* kvwb = qwb + 16384;                         // 32768
    short* pwb  = kvwb + 32768;                        // 16384
    short* w1b  = pwb + 16384;                         // 65536
    short* w2b  = w1b + 65536;                         // 65536
    float* outb = (float*)d_out;

    k_cvt<<<768, 256, 0, stream>>>(q_w, kv_w, proj_w, fc1_w, fc2_w, wcvt);
    k_ln_qkv_mfma<<<6272, 256, 0, stream>>>(x, v, n1g, n1b, nvg, nvb,
                                            qwb, q_b, kvwb, kv_b, qbuf, kbuf, vbuf);
    k_attn<<<dim3(4096, 4), 256, 0, stream>>>(qbuf, kbuf, vbuf, rpb);
    k_proj_mfma<<<6272, 256, 0, stream>>>(qbuf, pwb, proj_b, x, outb);
    k_mlp_mfma<<<6272, 256, 0, stream>>>(outb, n2g, n2b, w1b, fc1_b, w2b, fc2_b);
}